// Round 1
// baseline (690.050 us; speedup 1.0000x reference)
//
#include <hip/hip_runtime.h>

typedef float f32x4 __attribute__((ext_vector_type(4)));
typedef short bf16x8 __attribute__((ext_vector_type(8)));

#define INV_TEMP 14.285714285714286f
#define M_REF    14.285714285714286f

static constexpr size_t OUT_PRED   = 0;
static constexpr size_t OUT_LOSS   = 409600;
static constexpr size_t OUT_LOGITS = 409601;
static constexpr size_t OUT_LPROTO = 268849153;
static constexpr size_t OUT_NEWQ   = 269258753;
static constexpr size_t OUT_NPROTO = 277647361;

__device__ __forceinline__ unsigned f2bf(float x){
  unsigned u = __float_as_uint(x);
  return (u + 0x7fffu + ((u >> 16) & 1u)) >> 16;   // RTNE
}

// ---------- q [4096][128] f32 -> bf16 ----------
__global__ __launch_bounds__(256) void conv_q_k(const float* __restrict__ q,
                                                unsigned short* __restrict__ qbf){
  int i = blockIdx.x*256 + threadIdx.x;            // 8 floats per thread
  const float4* q4 = (const float4*)q;
  float4 a = q4[2*i], b = q4[2*i+1];
  int4 st;
  st.x = (int)(f2bf(a.x) | (f2bf(a.y) << 16));
  st.y = (int)(f2bf(a.z) | (f2bf(a.w) << 16));
  st.z = (int)(f2bf(b.x) | (f2bf(b.y) << 16));
  st.w = (int)(f2bf(b.z) | (f2bf(b.w) << 16));
  ((int4*)qbf)[i] = st;
}

// ---------- queue [128][65536] f32 -> qTbf [65536][128] bf16 (transpose) ----------
__global__ __launch_bounds__(256) void conv_qT_k(const float* __restrict__ queue,
                                                 unsigned short* __restrict__ qTbf){
  __shared__ float tile[128][65];
  const int jb = blockIdx.x, t = threadIdx.x;
  const int j0 = jb*64;
  for (int it=0; it<32; ++it){
    int idx = it*256 + t;
    int d = idx >> 6, j = idx & 63;
    tile[d][j] = queue[(size_t)d*65536 + j0 + j];
  }
  __syncthreads();
  for (int it=0; it<16; ++it){
    int pidx = it*256 + t;
    int j = pidx >> 6, d = (pidx & 63)*2;
    unsigned b0 = f2bf(tile[d][j]);
    unsigned b1 = f2bf(tile[d+1][j]);
    *(unsigned*)(qTbf + (size_t)(j0+j)*128 + d) = b0 | (b1 << 16);
  }
}

// ---------- l_pos: per-row dot(q,k)/TEMP -> logits[:,0] and scratch ----------
__global__ __launch_bounds__(64) void lpos_k(const float* __restrict__ q, const float* __restrict__ kk,
                                             float* __restrict__ out, float* __restrict__ lposw){
  const int r = blockIdx.x, l = threadIdx.x;
  const float2* q2 = (const float2*)(q + (size_t)r*128);
  const float2* k2 = (const float2*)(kk + (size_t)r*128);
  float2 a = q2[l], b = k2[l];
  float s = a.x*b.x + a.y*b.y;
  #pragma unroll
  for (int o=1;o<64;o<<=1) s += __shfl_xor(s, o, 64);
  if (l == 0){
    float v = s * INV_TEMP;
    out[OUT_LOGITS + (size_t)r*65537] = v;
    lposw[r] = v;
  }
}

// ---------- big GEMM: logits[:,1:] = (q @ queue)/TEMP, fused row sum-exp partials ----------
__global__ __launch_bounds__(256) void gemm_k(const unsigned short* __restrict__ qbf,
                                              const unsigned short* __restrict__ qTbf,
                                              float* __restrict__ out,
                                              float* __restrict__ partials){
  __shared__ unsigned char smem[65536];            // A 32KB | B 32KB, XOR-swizzled
  const int cb = blockIdx.x;                       // col tile (512)
  const int rb = blockIdx.y;                       // row tile (32)
  const int t  = threadIdx.x;
  const unsigned char* asrc = (const unsigned char*)qbf  + (size_t)rb*32768;
  const unsigned char* bsrc = (const unsigned char*)qTbf + (size_t)cb*32768;
  #pragma unroll
  for (int i=0;i<8;++i){
    int X = i*4096 + t*16;
    int row = X >> 8, off = X & 255;
    int sw = (row << 8) | (off ^ ((row & 7) << 4));
    *(bf16x8*)(smem + sw)         = *(const bf16x8*)(asrc + X);
    *(bf16x8*)(smem + 32768 + sw) = *(const bf16x8*)(bsrc + X);
  }
  __syncthreads();
  const int l = t & 63, w = t >> 6;
  const int wr = w >> 1, wc = w & 1;
  const int lrow = l & 15, lk = l >> 4;
  f32x4 acc[4][4];
  #pragma unroll
  for (int m=0;m<4;++m)
    #pragma unroll
    for (int n=0;n<4;++n) acc[m][n] = (f32x4){0.f,0.f,0.f,0.f};
  #pragma unroll
  for (int kk2=0; kk2<4; ++kk2){
    const int koff = kk2*64 + lk*16;
    bf16x8 af[4], bfr[4];
    #pragma unroll
    for (int m=0;m<4;++m){
      int row = wr*64 + m*16 + lrow;
      af[m] = *(const bf16x8*)(smem + ((row << 8) | (koff ^ ((row & 7) << 4))));
    }
    #pragma unroll
    for (int n=0;n<4;++n){
      int col = wc*64 + n*16 + lrow;
      bfr[n] = *(const bf16x8*)(smem + 32768 + ((col << 8) | (koff ^ ((col & 7) << 4))));
    }
    #pragma unroll
    for (int m=0;m<4;++m)
      #pragma unroll
      for (int n=0;n<4;++n)
        acc[m][n] = __builtin_amdgcn_mfma_f32_16x16x32_bf16(af[m], bfr[n], acc[m][n], 0, 0, 0);
  }
  __syncthreads();                                  // A/B LDS dead, reuse for row partials
  float* rowpart = (float*)smem;                    // [128][2]
  const size_t gcol = (size_t)cb*128 + wc*64 + lrow;
  #pragma unroll
  for (int m=0;m<4;++m){
    const int lr0 = wr*64 + m*16 + lk*4;
    #pragma unroll
    for (int r=0;r<4;++r){
      const size_t grow = (size_t)rb*128 + lr0 + r;
      float* p = out + OUT_LOGITS + grow*65537 + 1 + gcol;
      float s = 0.f;
      #pragma unroll
      for (int n=0;n<4;++n){
        float v = acc[m][n][r] * INV_TEMP;
        p[n*16] = v;
        s += __expf(v - M_REF);
      }
      #pragma unroll
      for (int o=1;o<16;o<<=1) s += __shfl_xor(s, o, 64);  // reduce over the 16 cols
      if (lrow == 0) rowpart[(lr0 + r)*2 + wc] = s;
    }
  }
  __syncthreads();
  if (t < 128) partials[(size_t)cb*4096 + rb*128 + t] = rowpart[t*2] + rowpart[t*2+1];
}

// ---------- block reduces (blockDim=128) ----------
__device__ __forceinline__ float bredmax(float v, float* red){
  int t = threadIdx.x; red[t] = v; __syncthreads();
  #pragma unroll
  for (int s=64;s>0;s>>=1){ if (t < s) red[t] = fmaxf(red[t], red[t+s]); __syncthreads(); }
  float r = red[0]; __syncthreads(); return r;
}
__device__ __forceinline__ float bredsum(float v, float* red){
  int t = threadIdx.x; red[t] = v; __syncthreads();
  #pragma unroll
  for (int s=64;s>0;s>>=1){ if (t < s) red[t] += red[t+s]; __syncthreads(); }
  float r = red[0]; __syncthreads(); return r;
}

// ---------- logits_proto + loss_proto/loss_cls rows + pred ----------
__global__ __launch_bounds__(128) void k6_k(const float* __restrict__ q, const float* __restrict__ outp_in,
                                            const float* __restrict__ protos, const float* __restrict__ labels,
                                            float* __restrict__ out, float* __restrict__ lcw,
                                            float* __restrict__ lpw){
  __shared__ float qs[128];
  __shared__ float red[128];
  const int r = blockIdx.x, t = threadIdx.x;
  qs[t] = q[(size_t)r*128 + t];
  __syncthreads();
  const bool act = t < 100;
  float p = 0.f;
  if (act){
    const float4* pr = (const float4*)(protos + (size_t)t*128);
    const float4* qv = (const float4*)qs;
    float s = 0.f;
    #pragma unroll 8
    for (int i=0;i<32;++i){ float4 a=qv[i], b=pr[i]; s += a.x*b.x + a.y*b.y + a.z*b.z + a.w*b.w; }
    p = s * INV_TEMP;
    out[OUT_LPROTO + (size_t)r*100 + t] = p;
  }
  const float lab = act ? labels[(size_t)r*100 + t] : 0.f;
  float mx  = bredmax(act ? p : -3.0e38f, red);
  float se  = bredsum(act ? __expf(p - mx) : 0.f, red);
  float lse = mx + logf(se);
  float lpv = bredsum(act ? lab * (p - lse) : 0.f, red);
  const float o = act ? outp_in[(size_t)r*100 + t] : 0.f;
  float mo   = bredmax(act ? o : -3.0e38f, red);
  float seo  = bredsum(act ? __expf(o - mo) : 0.f, red);
  float lseo = mo + logf(seo);
  float lcv  = bredsum(act ? lab * (o - lseo) : 0.f, red);
  if (act) out[OUT_PRED + (size_t)r*100 + t] = (t > 0 && o >= mo) ? 1.f : 0.f;
  if (t == 0){ lpw[r] = lpv; lcw[r] = lcv; }
}

// ---------- per-row logsumexp finish: inst row term ----------
__global__ __launch_bounds__(256) void rowsum_k(const float* __restrict__ partials,
                                                const float* __restrict__ lposw,
                                                float* __restrict__ instw){
  const int r = blockIdx.x*256 + threadIdx.x;
  float s = 0.f;
  for (int cb=0; cb<512; ++cb) s += partials[(size_t)cb*4096 + r];
  s += __expf(lposw[r] - M_REF);
  instw[r] = lposw[r] - M_REF - logf(s);            // log_softmax(logits)[r,0]
}

// ---------- sequential per-class prototype EMA + l2norm ----------
__global__ __launch_bounds__(128) void protos_k(const float* __restrict__ q, const float* __restrict__ protos,
                                                const int* __restrict__ targets, float* __restrict__ out){
  __shared__ int tg[4096];
  __shared__ float red[128];
  const int c = blockIdx.x, t = threadIdx.x;
  for (int i=t;i<4096;i+=128) tg[i] = targets[i];
  __syncthreads();
  float val = protos[(size_t)c*128 + t];
  if (c != 0){
    for (int n=0;n<4096;++n){
      if (tg[n] == c) val = val*0.999f + 0.001f*q[(size_t)n*128 + t];
    }
  }
  float ss = bredsum(val*val, red);
  float nrm = fmaxf(sqrtf(ss), 1e-12f);
  out[OUT_NPROTO + (size_t)c*128 + t] = val / nrm;
}

// ---------- final scalar loss ----------
__global__ __launch_bounds__(256) void loss_k(const float* __restrict__ lcw, const float* __restrict__ lpw,
                                              const float* __restrict__ instw, float* __restrict__ out){
  __shared__ float red[256];
  const int t = threadIdx.x;
  float s = 0.f;
  for (int r=t;r<4096;r+=256) s += lcw[r] + lpw[r] + instw[r];
  red[t] = s; __syncthreads();
  for (int k2=128;k2>0;k2>>=1){ if (t<k2) red[t] += red[t+k2]; __syncthreads(); }
  if (t==0) out[OUT_LOSS] = -red[0] * (1.0f/4096.0f);
}

// ---------- new_queue: copy (outside [ptr,ptr+4096)) ----------
__global__ __launch_bounds__(256) void newq_copy_k(const float* __restrict__ queue,
                                                   const int* __restrict__ ptrp,
                                                   float* __restrict__ out){
  size_t tid = (size_t)blockIdx.x*256 + threadIdx.x;
  const int ptr = *ptrp;
  for (size_t i=tid; i<(size_t)8388608; i += (size_t)gridDim.x*256){
    int j = (int)(i & 65535);
    int jm = j - ptr;
    if (jm >= 0 && jm < 4096) continue;             // filled by newq_kt_k
    out[OUT_NEWQ + i] = queue[i];
  }
}

// ---------- new_queue: k.T into columns [ptr, ptr+4096) ----------
__global__ __launch_bounds__(256) void newq_kt_k(const float* __restrict__ kk,
                                                 const int* __restrict__ ptrp,
                                                 float* __restrict__ out){
  __shared__ float tile[64][129];
  const int jb = blockIdx.x, t = threadIdx.x;
  const int ptr = *ptrp;
  for (int it=0; it<32; ++it){
    int idx = it*256 + t;
    int j = idx >> 7, d = idx & 127;
    tile[j][d] = kk[(size_t)(jb*64 + j)*128 + d];
  }
  __syncthreads();
  for (int it=0; it<32; ++it){
    int idx = it*256 + t;
    int d = idx >> 6, j = idx & 63;
    out[OUT_NEWQ + (size_t)d*65536 + (size_t)(ptr + jb*64 + j)] = tile[j][d];
  }
}

extern "C" void kernel_launch(void* const* d_in, const int* in_sizes, int n_in,
                              void* d_out, int out_size, void* d_ws, size_t ws_size,
                              hipStream_t stream){
  const float* q      = (const float*)d_in[0];
  const float* k      = (const float*)d_in[1];
  const float* outp   = (const float*)d_in[2];
  const float* queue  = (const float*)d_in[3];
  const float* protos = (const float*)d_in[4];
  const float* labels = (const float*)d_in[5];
  const int*   targets= (const int*)d_in[6];
  const int*   ptrp   = (const int*)d_in[7];
  float* out = (float*)d_out;

  // Scratch lives inside the new_queue OUTPUT region (33.5 MB; we need ~26.3 MB).
  // new_queue is written LAST, after every scratch consumer has finished.
  uintptr_t scr = (uintptr_t)(out + OUT_NEWQ);
  scr = (scr + 255) & ~(uintptr_t)255;
  unsigned short* qbf  = (unsigned short*)scr;                          // 1 MB
  unsigned short* qTbf = (unsigned short*)(scr + (1u<<20));             // 16 MB
  float* partials      = (float*)(scr + (1u<<20) + (16u<<20));          // 8 MB
  float* lposw         = (float*)(scr + 26214400u);                     // 16 KB
  float* lcw           = (float*)(scr + 26230784u);                     // 16 KB
  float* lpw           = (float*)(scr + 26247168u);                     // 16 KB
  float* instw         = (float*)(scr + 26263552u);                     // 16 KB

  conv_q_k <<<256,  256, 0, stream>>>(q, qbf);
  conv_qT_k<<<1024, 256, 0, stream>>>(queue, qTbf);
  lpos_k   <<<4096,  64, 0, stream>>>(q, k, out, lposw);
  gemm_k   <<<dim3(512,32), 256, 0, stream>>>(qbf, qTbf, out, partials);
  k6_k     <<<4096, 128, 0, stream>>>(q, outp, protos, labels, out, lcw, lpw);
  rowsum_k <<<16,   256, 0, stream>>>(partials, lposw, instw);
  protos_k <<<100,  128, 0, stream>>>(q, protos, targets, out);
  loss_k   <<<1,    256, 0, stream>>>(lcw, lpw, instw, out);
  newq_copy_k<<<4096, 256, 0, stream>>>(queue, ptrp, out);
  newq_kt_k  <<<64,   256, 0, stream>>>(k, ptrp, out);

  (void)in_sizes; (void)n_in; (void)d_ws; (void)ws_size; (void)out_size;
}